// Round 1
// baseline (296.517 us; speedup 1.0000x reference)
//
#include <hip/hip_runtime.h>

// Beamform: 4 channels of interleaved complex f32; per 20-complex-sample unit
// (160 B from ONE channel) a (1x4)@(4x5) complex combine with weight vector
// bf (8 floats, re/im interleaved) producing 10 floats [re0..re4, im0..im4].
//
// Round 3: make the global-memory side structurally identical to a float4
// streaming copy (the 6.3 TB/s m13 pattern). Previous round did 8-B loads
// spread over 2048-B spans + 4-B stores at stride 40 -> 3.5 TB/s effective.
//
//   Phase 1: 256 threads stage 256 units (40 KiB) via 10 coalesced float4
//            loads/thread, ds_write_b128 with XOR swizzle j = i ^ ((i/10)&7).
//            Swizzle is bijective within each aligned 8-float4 (128 B) group
//            (unit boundaries land on even slot offsets -> XOR-1 pairs never
//            straddle), and makes BOTH the linear writes and the per-unit
//            strided reads conflict-free (slot = ((2t+k)&7) ^ (t&7) is a
//            bijection on t&7 for every k; linear layout would be 16-way).
//   Phase 2: thread t consumes unit t (10x ds_read_b128), 4x5 complex MACs.
//   Phase 3: outputs staged to LDS as float2 at stride 5 (gcd(5,16)=1 ->
//            conflict-free), then flat coalesced float2 stream to global.
//
// LDS 40960 B -> exactly 4 WG/CU (160 KiB), 16 waves/CU.

constexpr int UNITS   = 256;   // 20-complex-sample units per workgroup
constexpr int THREADS = 256;

__global__ __launch_bounds__(THREADS) void beamform_kernel(
    const float* __restrict__ in0, const float* __restrict__ in1,
    const float* __restrict__ in2, const float* __restrict__ in3,
    const float* __restrict__ bf, float* __restrict__ out,
    int blocksPerChannel)
{
    __shared__ float4 lds4[UNITS * 10];   // 40 KiB

    const int tid    = threadIdx.x;
    const int ch     = blockIdx.y;
    const int wgBase = blockIdx.x * UNITS;
    const int validUnits = min(UNITS, blocksPerChannel - wgBase);

    const float* __restrict__ in =
        (ch == 0) ? in0 : (ch == 1) ? in1 : (ch == 2) ? in2 : in3;
    const float4* __restrict__ g4 =
        reinterpret_cast<const float4*>(in) + (size_t)wgBase * 10;

    // Wave-uniform beamforming weights (r = 0..3).
    const float4 blo = reinterpret_cast<const float4*>(bf)[0];
    const float4 bhi = reinterpret_cast<const float4*>(bf)[1];
    const float br[4] = {blo.x, blo.z, bhi.x, bhi.z};
    const float bi[4] = {blo.y, blo.w, bhi.y, bhi.w};

    // ---- Phase 1: global -> LDS (swizzled), pure coalesced float4 ----
    if (validUnits == UNITS) {
        float4 v[10];
        #pragma unroll
        for (int k = 0; k < 10; ++k)
            v[k] = g4[k * THREADS + tid];
        #pragma unroll
        for (int k = 0; k < 10; ++k) {
            const int i = k * THREADS + tid;
            lds4[i ^ ((i / 10) & 7)] = v[k];
        }
    } else {
        const int nf4 = validUnits * 10;
        #pragma unroll
        for (int k = 0; k < 10; ++k) {
            const int i = k * THREADS + tid;
            if (i < nf4) {
                const float4 v = g4[i];
                lds4[i ^ ((i / 10) & 7)] = v;
            }
        }
    }
    __syncthreads();

    // ---- Phase 2: thread t consumes unit t from LDS ----
    float re[5] = {0.f, 0.f, 0.f, 0.f, 0.f};
    float im[5] = {0.f, 0.f, 0.f, 0.f, 0.f};
    const bool active = (tid < validUnits);
    if (active) {
        #pragma unroll
        for (int k = 0; k < 10; ++k) {
            const float4 w = lds4[(tid * 10 + k) ^ (tid & 7)];
            const float e[4] = {w.x, w.y, w.z, w.w};
            #pragma unroll
            for (int q = 0; q < 4; ++q) {
                // f = 10*r + 2*c + s  (all compile-time after unrolling)
                const int f   = 4 * k + q;
                const int r   = f / 10;
                const int rem = f - 10 * r;
                const int c   = rem >> 1;
                if ((rem & 1) == 0) {        // real sample
                    re[c] += br[r] * e[q];
                    im[c] += bi[r] * e[q];
                } else {                     // imag sample
                    re[c] -= bi[r] * e[q];
                    im[c] += br[r] * e[q];
                }
            }
        }
    }
    __syncthreads();   // all phase-2 LDS reads complete before reuse

    // ---- Phase 3: outputs -> LDS (float2, stride 5: conflict-free) ----
    float2* lds2 = reinterpret_cast<float2*>(lds4);
    if (active) {
        // unit output order: [re0..re4, im0..im4] -> float2 pairs
        lds2[tid * 5 + 0] = make_float2(re[0], re[1]);
        lds2[tid * 5 + 1] = make_float2(re[2], re[3]);
        lds2[tid * 5 + 2] = make_float2(re[4], im[0]);
        lds2[tid * 5 + 3] = make_float2(im[1], im[2]);
        lds2[tid * 5 + 4] = make_float2(im[3], im[4]);
    }
    __syncthreads();

    // ---- Phase 4: LDS -> global, flat coalesced float2 stream ----
    float2* __restrict__ gout2 =
        reinterpret_cast<float2*>(out) +
        ((size_t)ch * blocksPerChannel + wgBase) * 5;
    const int nf2 = validUnits * 5;
    if (nf2 == UNITS * 5) {
        #pragma unroll
        for (int k = 0; k < 5; ++k) {
            const int i = k * THREADS + tid;
            gout2[i] = lds2[i];
        }
    } else {
        #pragma unroll
        for (int k = 0; k < 5; ++k) {
            const int i = k * THREADS + tid;
            if (i < nf2) gout2[i] = lds2[i];
        }
    }
}

extern "C" void kernel_launch(void* const* d_in, const int* in_sizes, int n_in,
                              void* d_out, int out_size, void* d_ws, size_t ws_size,
                              hipStream_t stream)
{
    const float* in0 = (const float*)d_in[0];
    const float* in1 = (const float*)d_in[1];
    const float* in2 = (const float*)d_in[2];
    const float* in3 = (const float*)d_in[3];
    const float* bf  = (const float*)d_in[4];
    float* out = (float*)d_out;

    const int len = in_sizes[0];               // 20,000,000 interleaved floats
    const int blocksPerChannel = len / 40;     // 500,000 units / channel

    dim3 grid((blocksPerChannel + UNITS - 1) / UNITS, 4, 1);
    beamform_kernel<<<grid, dim3(THREADS, 1, 1), 0, stream>>>(
        in0, in1, in2, in3, bf, out, blocksPerChannel);
}